// Round 15
// baseline (199.429 us; speedup 1.0000x reference)
//
#include <hip/hip_runtime.h>
#include <math.h>

#define CIN   32
#define COUT  32
#define HH    256
#define WW    256
#define BB    16
#define SDIM  512

#define XT    16
#define YT    16
#define NXT   16
#define NTILE 256           // 16x16 tiles per (b,co)

typedef __attribute__((ext_vector_type(8))) short bf16x8;
typedef __attribute__((ext_vector_type(4))) float f32x4;
typedef __attribute__((ext_vector_type(8))) unsigned short u16x8;

__device__ __forceinline__ unsigned bf16_rne_bits(float x) {
    unsigned u = __float_as_uint(x);
    return (u + 0x7fffu + ((u >> 16) & 1u)) >> 16;   // round-nearest-even bf16
}

// ---------------- prep: s = style @ (mod_weight*mscale)^T + bias ----------------
// also zeroes the 64B OOB-source buffer used by conv's global_load_lds staging
__global__ __launch_bounds__(512) void prep_s_kernel(
    const float* __restrict__ style,
    const float* __restrict__ mod_weight,
    const float* __restrict__ mod_bias,
    float* __restrict__ s_out,
    float* __restrict__ zbuf) {
    int t = threadIdx.x;            // t -> (b, ci)
    if (t < 16) zbuf[t] = 0.f;
    int b = t >> 5, ci = t & 31;
    const float mscale = 0.044194173824159216f;  // 1/sqrt(512)
    const float* st = style + b * SDIM;
    const float* mw = mod_weight + ci * SDIM;
    float acc = 0.f;
    for (int d = 0; d < SDIM; d += 4) {
        acc += st[d]   * mw[d]
             + st[d+1] * mw[d+1]
             + st[d+2] * mw[d+2]
             + st[d+3] * mw[d+3];
    }
    s_out[t] = acc * mscale + mod_bias[ci];
}

// ---------------- prep: pack per-(b,window) modulated weights as bf16 hi/lo ------
// Layout: Wk[((b*9 + w)*2 + part)*1024 + co*32 + ci]  (ushort bf16 bits)
__global__ __launch_bounds__(256) void prep_w_kernel(
    const float* __restrict__ weight,
    const float* __restrict__ s,
    unsigned short* __restrict__ Wk) {
    int idx = blockIdx.x * 256 + threadIdx.x;   // over 16*32*32*9 = 147456
    if (idx >= BB * COUT * CIN * 9) return;
    const float wscale = 0.05892556509887896f;  // 1/sqrt(32*3*3)
    int b  = idx / (COUT * CIN * 9);
    int r  = idx % (COUT * CIN * 9);
    int co = r / (CIN * 9);
    int r2 = r % (CIN * 9);
    int ci = r2 / 9;
    int w  = r2 % 9;
    float wm = wscale * weight[co * (CIN * 9) + ci * 9 + w] * s[b * CIN + ci];
    unsigned hb = bf16_rne_bits(wm);
    float hif = __uint_as_float(hb << 16);
    unsigned lb = bf16_rne_bits(wm - hif);
    int base = ((b * 9 + w) * 2) * 1024 + co * 32 + ci;
    Wk[base]        = (unsigned short)hb;   // part 0: hi
    Wk[base + 1024] = (unsigned short)lb;   // part 1: lo
}

// ---------------- repack v2: NCHW fp32 -> slot-permuted NHWC bf16 --------------
// LDS-bounce transpose: stage A coalesced float4 reads -> lt[x][ci] (stride 40);
// stage B 16B LDS reads (<=2-way banks) -> perfectly contiguous 16B stores.
// chunk(b,gy,gx) = 64B of 32 ci; octet o at slot (o + ((gx+1)>>1))&3.
__global__ __launch_bounds__(256) void repack_kernel(
    const float* __restrict__ input,
    unsigned short* __restrict__ nhwc) {
    __shared__ __align__(16) unsigned short lt[256 * 40];   // 20 KB
    const int tid = threadIdx.x;
    const int gy = blockIdx.x & 255;
    const int b  = blockIdx.x >> 8;

    // stage A: 512 tasks (8 ci-quads x 64 float4), 2 per thread
    #pragma unroll
    for (int it = 0; it < 2; ++it) {
        int idx = it * 256 + tid;
        int xf  = idx & 63;             // x = 4*xf..+3
        int cg  = idx >> 6;             // ci = 4*cg..+3
        const float* ip = input + (((b * 32 + cg * 4) * 256 + gy) * 256) + xf * 4;
        float4 v0 = *(const float4*)(ip);
        float4 v1 = *(const float4*)(ip + 65536);
        float4 v2 = *(const float4*)(ip + 131072);
        float4 v3 = *(const float4*)(ip + 196608);
        float a0[4] = {v0.x, v0.y, v0.z, v0.w};
        float a1[4] = {v1.x, v1.y, v1.z, v1.w};
        float a2[4] = {v2.x, v2.y, v2.z, v2.w};
        float a3[4] = {v3.x, v3.y, v3.z, v3.w};
        #pragma unroll
        for (int m = 0; m < 4; ++m) {
            uint2 p;
            p.x = bf16_rne_bits(a0[m]) | (bf16_rne_bits(a1[m]) << 16);
            p.y = bf16_rne_bits(a2[m]) | (bf16_rne_bits(a3[m]) << 16);
            *(uint2*)&lt[(xf * 4 + m) * 40 + cg * 4] = p;
        }
    }
    __syncthreads();

    // stage B: 1024 tasks (256 gx x 4 slots), 4 per thread; lanes -> contiguous
    unsigned short* cb = nhwc + (((((b << 8) + gy) << 8)) << 5);
    #pragma unroll
    for (int it = 0; it < 4; ++it) {
        int idx  = it * 256 + tid;
        int slot = idx & 3;
        int gx   = idx >> 2;
        int o    = (slot - ((gx + 1) >> 1)) & 3;
        bf16x8 v = *(const bf16x8*)&lt[gx * 40 + o * 8];
        *(bf16x8*)(cb + (gx << 5) + slot * 8) = v;
    }
}

// ---------------- MFMA conv: global_load_lds staging -----------------------------
// grid 4096 (XCD-swizzled), 4 waves, 6 blocks/CU (~21KB LDS).
// Staging: 1296 x 16B direct global->LDS DMA; LDS dest linear (base+lane*16),
// swizzle pre-baked in nhwc; OOB lanes read a 64B zero buffer.
// NOTE: (256,6) is the measured local optimum — (512,8) and (256,7) both
// trigger register-cap spills (+50..250us). Do not tighten launch bounds.
__global__ __launch_bounds__(256, 6) void conv_mfma_kernel(
    const unsigned short* __restrict__ nhwc,
    const unsigned short* __restrict__ Wk,
    const float* __restrict__ zbuf,
    unsigned short* __restrict__ bfout,
    float2* __restrict__ partials) {

    __shared__ __align__(16) unsigned short xlds[18 * 576];
    __shared__ float2 stats[4 * 32];

    const int tid = threadIdx.x;
    // bijective XCD swizzle: each XCD gets 512 consecutive sw ids (2 b-slices)
    const int wg = blockIdx.x;
    const int sw = (wg & 7) * 512 + (wg >> 3);
    const int b  = sw >> 8;
    const int yt = (sw >> 4) & 15;
    const int xt = sw & 15;

    const int x0 = xt * XT, y0 = yt * YT;
    const int t  = tid & 15;
    const int g  = (tid >> 4) & 3;
    const int wv = tid >> 6;
    const int f  = wv & 1;
    const int rbase = 8 * (wv >> 1);

    // ---- staging: 1296 x 16B global->LDS DMA (6 per thread) ----
    #pragma unroll
    for (int it = 0; it < 6; ++it) {
        int idx = it * 256 + tid;
        if (idx < 1296) {
            int s  = idx & 3;
            int cu = idx >> 2;          // y*18 + u
            int u  = cu % 18;
            int y  = cu / 18;
            int gy = y0 - 1 + y, gx = x0 - 1 + u;
            bool ok = ((unsigned)gy < 256u) && ((unsigned)gx < 256u);
            const unsigned short* src = ok
                ? nhwc + (((((b << 8) + gy) << 8) + gx) << 5) + s * 8
                : (const unsigned short*)zbuf + s * 8;
            __builtin_amdgcn_global_load_lds(
                (const __attribute__((address_space(1))) unsigned int*)src,
                (__attribute__((address_space(3))) unsigned int*)
                    ((char*)xlds + (idx << 4)),
                16, 0, 0);
        }
    }
    __syncthreads();

    // ---- compute: 3 kw-passes (compiler-unrolled/pipelined), 144 MFMA ----
    f32x4 acc[8];
    #pragma unroll
    for (int i = 0; i < 8; ++i) acc[i] = (f32x4){0.f, 0.f, 0.f, 0.f};

    #pragma unroll
    for (int kw = 0; kw < 3; ++kw) {
        const int u = t + kw;                    // 0..17, always staged
        const int slot = (g + (u >> 1)) & 3;

        bf16x8 wf[3][2];
        const unsigned short* wb =
            Wk + (b * 9 * 2) * 1024 + f * 512 + t * 32 + g * 8;
        #pragma unroll
        for (int kh = 0; kh < 3; ++kh) {
            wf[kh][0] = *(const bf16x8*)(wb + ((kh * 3 + kw) * 2 + 0) * 1024);
            wf[kh][1] = *(const bf16x8*)(wb + ((kh * 3 + kw) * 2 + 1) * 1024);
        }

        bf16x8 xv[10];
        #pragma unroll
        for (int y = 0; y < 10; ++y)
            xv[y] = *(const bf16x8*)&xlds[(rbase + y) * 576 + u * 32 + slot * 8];

        #pragma unroll
        for (int kh = 0; kh < 3; ++kh)
            #pragma unroll
            for (int i = 0; i < 8; ++i) {
                acc[i] = __builtin_amdgcn_mfma_f32_16x16x32_bf16(
                    wf[kh][0], xv[i + kh], acc[i], 0, 0, 0);
                acc[i] = __builtin_amdgcn_mfma_f32_16x16x32_bf16(
                    wf[kh][1], xv[i + kh], acc[i], 0, 0, 0);
            }
    }

    // ---- epilogue: bf16 stores + stats ----
    float s_[4] = {0.f, 0.f, 0.f, 0.f}, q_[4] = {0.f, 0.f, 0.f, 0.f};
    #pragma unroll
    for (int i = 0; i < 8; ++i) {
        const int gy = y0 + rbase + i;
        #pragma unroll
        for (int r = 0; r < 4; ++r) {
            float v = acc[i][r];
            const int off = (b * 32 + 16 * f + 4 * g + r) * 65536 + gy * 256 + x0 + t;
            bfout[off] = (unsigned short)bf16_rne_bits(v);
            s_[r] += v;
            q_[r] += v * v;
        }
    }
    #pragma unroll
    for (int r = 0; r < 4; ++r) {
        #pragma unroll
        for (int off = 1; off < 16; off <<= 1) {
            s_[r] += __shfl_xor(s_[r], off);
            q_[r] += __shfl_xor(q_[r], off);
        }
    }
    if (t == 0) {
        #pragma unroll
        for (int r = 0; r < 4; ++r)
            stats[wv * 32 + 16 * f + 4 * g + r] = make_float2(s_[r], q_[r]);
    }
    __syncthreads();
    if (tid < 32) {
        int w0 = (tid < 16) ? 0 : 1;            // waves 0/2 own co<16, 1/3 co>=16
        float2 a = stats[w0 * 32 + tid];
        float2 c = stats[(w0 + 2) * 32 + tid];
        partials[(b * 32 + tid) * NTILE + yt * NXT + xt] =
            make_float2(a.x + c.x, a.y + c.y);
    }
}

// ---------------- fold tile partials -> inv std ----------------
__global__ __launch_bounds__(256) void reduce_kernel(
    const float2* __restrict__ partials,
    float* __restrict__ inv_std) {
    int t = blockIdx.x * 256 + threadIdx.x;
    if (t >= BB * COUT) return;
    float s = 0.f, sq = 0.f;
    for (int k = 0; k < NTILE; ++k) {
        float2 p = partials[t * NTILE + k];
        s += p.x; sq += p.y;
    }
    const float N = 65536.f;
    float var = (sq - s * s / N) / (N - 1.f);   // unbiased (ddof=1)
    inv_std[t] = 1.0f / sqrtf(var);
}

// ---------------- scale: bf16 ws -> fp32 out ----------------
__global__ __launch_bounds__(256) void scale_bf16_kernel(
    const unsigned short* __restrict__ bf,
    const float* __restrict__ inv_std,
    float* __restrict__ out) {
    const int n8 = BB * COUT * HH * WW / 8;     // 4194304
    for (int i = blockIdx.x * 256 + threadIdx.x; i < n8; i += gridDim.x * 256) {
        float m = inv_std[i >> 13];             // (i*8)>>16
        u16x8 v = *(const u16x8*)&bf[i * 8];
        float4 a, c;
        a.x = __uint_as_float(((unsigned)v[0]) << 16) * m;
        a.y = __uint_as_float(((unsigned)v[1]) << 16) * m;
        a.z = __uint_as_float(((unsigned)v[2]) << 16) * m;
        a.w = __uint_as_float(((unsigned)v[3]) << 16) * m;
        c.x = __uint_as_float(((unsigned)v[4]) << 16) * m;
        c.y = __uint_as_float(((unsigned)v[5]) << 16) * m;
        c.z = __uint_as_float(((unsigned)v[6]) << 16) * m;
        c.w = __uint_as_float(((unsigned)v[7]) << 16) * m;
        *(float4*)&out[i * 8]     = a;
        *(float4*)&out[i * 8 + 4] = c;
    }
}

extern "C" void kernel_launch(void* const* d_in, const int* in_sizes, int n_in,
                              void* d_out, int out_size, void* d_ws, size_t ws_size,
                              hipStream_t stream) {
    const float* input      = (const float*)d_in[0];
    const float* style      = (const float*)d_in[1];
    const float* weight     = (const float*)d_in[2];
    const float* mod_weight = (const float*)d_in[3];
    const float* mod_bias   = (const float*)d_in[4];
    float* out = (float*)d_out;
    char*  ws  = (char*)d_ws;

    float*          s        = (float*)ws;                        // 2048 B
    unsigned short* Wk       = (unsigned short*)(ws + 2048);      // 589824 B
    float2*         partials = (float2*)(ws + 2048 + 589824);     // 1048576 B
    float*          inv      = (float*)(ws + 2048 + 589824 + 1048576);  // 2048 B
    float*          zbuf     = (float*)(ws + 2048 + 589824 + 1048576 + 2048); // 64 B
    const size_t    bf_off   = 2048 + 589824 + 1048576 + 2048 + 64;
    unsigned short* bfout    = (unsigned short*)(ws + bf_off);    // 67108864 B

    // NHWC bf16 intermediate lives in d_out's first 67MB; conv consumes it
    // before scale_bf16 overwrites all of d_out. Deterministic across replays.
    unsigned short* nhwc = (unsigned short*)d_out;

    prep_s_kernel<<<1, 512, 0, stream>>>(style, mod_weight, mod_bias, s, zbuf);
    prep_w_kernel<<<(BB * COUT * CIN * 9 + 255) / 256, 256, 0, stream>>>(
        weight, s, Wk);

    repack_kernel<<<4096, 256, 0, stream>>>(input, nhwc);
    conv_mfma_kernel<<<4096, 256, 0, stream>>>(nhwc, Wk, zbuf, bfout, partials);

    reduce_kernel<<<2, 256, 0, stream>>>(partials, inv);
    scale_bf16_kernel<<<2048, 256, 0, stream>>>(bfout, inv, out);
}

// Round 16
// 175.963 us; speedup vs baseline: 1.1334x; 1.1334x over previous
//
#include <hip/hip_runtime.h>
#include <math.h>

#define CIN   32
#define COUT  32
#define HH    256
#define WW    256
#define BB    16
#define SDIM  512

#define XT    16
#define YT    16
#define NXT   16
#define NTILE 256           // 16x16 tiles per (b,co)

typedef __attribute__((ext_vector_type(8))) short bf16x8;
typedef __attribute__((ext_vector_type(4))) float f32x4;
typedef __attribute__((ext_vector_type(8))) unsigned short u16x8;

__device__ __forceinline__ unsigned bf16_rne_bits(float x) {
    unsigned u = __float_as_uint(x);
    return (u + 0x7fffu + ((u >> 16) & 1u)) >> 16;   // round-nearest-even bf16
}

// ---------------- prep: s = style @ (mod_weight*mscale)^T + bias ----------------
// also zeroes the 64B OOB-source buffer used by conv's global_load_lds staging
__global__ __launch_bounds__(512) void prep_s_kernel(
    const float* __restrict__ style,
    const float* __restrict__ mod_weight,
    const float* __restrict__ mod_bias,
    float* __restrict__ s_out,
    float* __restrict__ zbuf) {
    int t = threadIdx.x;            // t -> (b, ci)
    if (t < 16) zbuf[t] = 0.f;
    int b = t >> 5, ci = t & 31;
    const float mscale = 0.044194173824159216f;  // 1/sqrt(512)
    const float* st = style + b * SDIM;
    const float* mw = mod_weight + ci * SDIM;
    float acc = 0.f;
    for (int d = 0; d < SDIM; d += 4) {
        acc += st[d]   * mw[d]
             + st[d+1] * mw[d+1]
             + st[d+2] * mw[d+2]
             + st[d+3] * mw[d+3];
    }
    s_out[t] = acc * mscale + mod_bias[ci];
}

// ---------------- prep: pack per-(b,window) modulated weights as bf16 hi/lo ------
// Layout: Wk[((b*9 + w)*2 + part)*1024 + co*32 + ci]  (ushort bf16 bits)
__global__ __launch_bounds__(256) void prep_w_kernel(
    const float* __restrict__ weight,
    const float* __restrict__ s,
    unsigned short* __restrict__ Wk) {
    int idx = blockIdx.x * 256 + threadIdx.x;   // over 16*32*32*9 = 147456
    if (idx >= BB * COUT * CIN * 9) return;
    const float wscale = 0.05892556509887896f;  // 1/sqrt(32*3*3)
    int b  = idx / (COUT * CIN * 9);
    int r  = idx % (COUT * CIN * 9);
    int co = r / (CIN * 9);
    int r2 = r % (CIN * 9);
    int ci = r2 / 9;
    int w  = r2 % 9;
    float wm = wscale * weight[co * (CIN * 9) + ci * 9 + w] * s[b * CIN + ci];
    unsigned hb = bf16_rne_bits(wm);
    float hif = __uint_as_float(hb << 16);
    unsigned lb = bf16_rne_bits(wm - hif);
    int base = ((b * 9 + w) * 2) * 1024 + co * 32 + ci;
    Wk[base]        = (unsigned short)hb;   // part 0: hi
    Wk[base + 1024] = (unsigned short)lb;   // part 1: lo
}

// ---------------- repack v2: NCHW fp32 -> slot-permuted NHWC bf16 --------------
// LDS-bounce transpose: stage A coalesced float4 reads -> lt[x][ci] (stride 40);
// stage B 16B LDS reads (<=2-way banks) -> perfectly contiguous 16B stores.
// chunk(b,gy,gx) = 64B of 32 ci; octet o at slot (o + ((gx+1)>>1))&3.
__global__ __launch_bounds__(256) void repack_kernel(
    const float* __restrict__ input,
    unsigned short* __restrict__ nhwc) {
    __shared__ __align__(16) unsigned short lt[256 * 40];   // 20 KB
    const int tid = threadIdx.x;
    const int gy = blockIdx.x & 255;
    const int b  = blockIdx.x >> 8;

    // stage A: 512 tasks (8 ci-quads x 64 float4), 2 per thread
    #pragma unroll
    for (int it = 0; it < 2; ++it) {
        int idx = it * 256 + tid;
        int xf  = idx & 63;             // x = 4*xf..+3
        int cg  = idx >> 6;             // ci = 4*cg..+3
        const float* ip = input + (((b * 32 + cg * 4) * 256 + gy) * 256) + xf * 4;
        float4 v0 = *(const float4*)(ip);
        float4 v1 = *(const float4*)(ip + 65536);
        float4 v2 = *(const float4*)(ip + 131072);
        float4 v3 = *(const float4*)(ip + 196608);
        float a0[4] = {v0.x, v0.y, v0.z, v0.w};
        float a1[4] = {v1.x, v1.y, v1.z, v1.w};
        float a2[4] = {v2.x, v2.y, v2.z, v2.w};
        float a3[4] = {v3.x, v3.y, v3.z, v3.w};
        #pragma unroll
        for (int m = 0; m < 4; ++m) {
            uint2 p;
            p.x = bf16_rne_bits(a0[m]) | (bf16_rne_bits(a1[m]) << 16);
            p.y = bf16_rne_bits(a2[m]) | (bf16_rne_bits(a3[m]) << 16);
            *(uint2*)&lt[(xf * 4 + m) * 40 + cg * 4] = p;
        }
    }
    __syncthreads();

    // stage B: 1024 tasks (256 gx x 4 slots), 4 per thread; lanes -> contiguous
    unsigned short* cb = nhwc + (((((b << 8) + gy) << 8)) << 5);
    #pragma unroll
    for (int it = 0; it < 4; ++it) {
        int idx  = it * 256 + tid;
        int slot = idx & 3;
        int gx   = idx >> 2;
        int o    = (slot - ((gx + 1) >> 1)) & 3;
        bf16x8 v = *(const bf16x8*)&lt[gx * 40 + o * 8];
        *(bf16x8*)(cb + (gx << 5) + slot * 8) = v;
    }
}

// ---------------- MFMA conv: 2 x-tiles/block, double-buffered DMA staging ------
// grid 2048 (XCD-swizzled), 4 waves, 3 blocks/CU (42.5KB LDS).
// T3 2-phase: STAGE(buf0) -> bar -> STAGE(buf1 async) -> compute tile0
// (tile0's stats barrier drains buf1's DMA, hidden under MFMA) -> compute tile1.
// NOTE: (512,8)/(256,7) launch bounds spill (+50..250us); kw loop full-unroll
// regressed +28us (r15). Keep (256,3-cap) and unroll 1.
__global__ __launch_bounds__(256, 3) void conv_mfma_kernel(
    const unsigned short* __restrict__ nhwc,
    const unsigned short* __restrict__ Wk,
    const float* __restrict__ zbuf,
    unsigned short* __restrict__ bfout,
    float2* __restrict__ partials) {

    __shared__ __align__(16) unsigned short xlds[2][18 * 576];  // 2 x 20736 B
    __shared__ float2 stats[4 * 32];

    const int tid = threadIdx.x;
    // bijective XCD swizzle: each XCD gets 256 consecutive sw ids (2 b-slices)
    const int wg  = blockIdx.x;
    const int sw  = (wg & 7) * 256 + (wg >> 3);
    const int b   = sw >> 7;
    const int yt  = (sw >> 3) & 15;
    const int xtp = sw & 7;           // x-tile pair: xt = 2*xtp, 2*xtp+1

    const int y0 = yt * YT;
    const int t  = tid & 15;
    const int g  = (tid >> 4) & 3;
    const int wv = tid >> 6;
    const int f  = wv & 1;
    const int rbase = 8 * (wv >> 1);

    // ---- staging helper: 1296 x 16B global->LDS DMA into buf ----
    auto STAGE = [&](int buf, int x0) {
        #pragma unroll
        for (int it = 0; it < 6; ++it) {
            int idx = it * 256 + tid;
            if (idx < 1296) {
                int s  = idx & 3;
                int cu = idx >> 2;          // y*18 + u
                int u  = cu % 18;
                int y  = cu / 18;
                int gy = y0 - 1 + y, gx = x0 - 1 + u;
                bool ok = ((unsigned)gy < 256u) && ((unsigned)gx < 256u);
                const unsigned short* src = ok
                    ? nhwc + (((((b << 8) + gy) << 8) + gx) << 5) + s * 8
                    : (const unsigned short*)zbuf + s * 8;
                __builtin_amdgcn_global_load_lds(
                    (const __attribute__((address_space(1))) unsigned int*)src,
                    (__attribute__((address_space(3))) unsigned int*)
                        ((char*)&xlds[buf][0] + (idx << 4)),
                    16, 0, 0);
            }
        }
    };

    // ---- compute + epilogue for one tile ----
    auto PROCESS = [&](int buf, int x0, int xt) {
        f32x4 acc[8];
        #pragma unroll
        for (int i = 0; i < 8; ++i) acc[i] = (f32x4){0.f, 0.f, 0.f, 0.f};

        #pragma unroll 1
        for (int kw = 0; kw < 3; ++kw) {
            const int u = t + kw;                    // 0..17, always staged
            const int slot = (g + (u >> 1)) & 3;

            bf16x8 wf[3][2];
            const unsigned short* wb =
                Wk + (b * 9 * 2) * 1024 + f * 512 + t * 32 + g * 8;
            #pragma unroll
            for (int kh = 0; kh < 3; ++kh) {
                wf[kh][0] = *(const bf16x8*)(wb + ((kh * 3 + kw) * 2 + 0) * 1024);
                wf[kh][1] = *(const bf16x8*)(wb + ((kh * 3 + kw) * 2 + 1) * 1024);
            }

            bf16x8 xv[10];
            #pragma unroll
            for (int y = 0; y < 10; ++y)
                xv[y] = *(const bf16x8*)
                    &xlds[buf][(rbase + y) * 576 + u * 32 + slot * 8];

            #pragma unroll
            for (int kh = 0; kh < 3; ++kh)
                #pragma unroll
                for (int i = 0; i < 8; ++i) {
                    acc[i] = __builtin_amdgcn_mfma_f32_16x16x32_bf16(
                        wf[kh][0], xv[i + kh], acc[i], 0, 0, 0);
                    acc[i] = __builtin_amdgcn_mfma_f32_16x16x32_bf16(
                        wf[kh][1], xv[i + kh], acc[i], 0, 0, 0);
                }
        }

        float s_[4] = {0.f, 0.f, 0.f, 0.f}, q_[4] = {0.f, 0.f, 0.f, 0.f};
        #pragma unroll
        for (int i = 0; i < 8; ++i) {
            const int gy = y0 + rbase + i;
            #pragma unroll
            for (int r = 0; r < 4; ++r) {
                float v = acc[i][r];
                const int off =
                    (b * 32 + 16 * f + 4 * g + r) * 65536 + gy * 256 + x0 + t;
                bfout[off] = (unsigned short)bf16_rne_bits(v);
                s_[r] += v;
                q_[r] += v * v;
            }
        }
        #pragma unroll
        for (int r = 0; r < 4; ++r) {
            #pragma unroll
            for (int off = 1; off < 16; off <<= 1) {
                s_[r] += __shfl_xor(s_[r], off);
                q_[r] += __shfl_xor(q_[r], off);
            }
        }
        if (t == 0) {
            #pragma unroll
            for (int r = 0; r < 4; ++r)
                stats[wv * 32 + 16 * f + 4 * g + r] = make_float2(s_[r], q_[r]);
        }
        __syncthreads();   // stats ready; also drains any in-flight DMA (buf1)
        if (tid < 32) {
            int w0 = (tid < 16) ? 0 : 1;        // waves 0/2 own co<16, 1/3 co>=16
            float2 a = stats[w0 * 32 + tid];
            float2 c = stats[(w0 + 2) * 32 + tid];
            partials[(b * 32 + tid) * NTILE + yt * NXT + xt] =
                make_float2(a.x + c.x, a.y + c.y);
        }
        __syncthreads();   // protect stats from next tile's overwrite
    };

    const int xt0 = 2 * xtp, xt1 = 2 * xtp + 1;
    STAGE(0, xt0 * XT);
    __syncthreads();                 // buf0 ready
    STAGE(1, xt1 * XT);              // async issue; drained inside PROCESS(0)
    PROCESS(0, xt0 * XT, xt0);
    PROCESS(1, xt1 * XT, xt1);
}

// ---------------- fold tile partials -> inv std ----------------
__global__ __launch_bounds__(256) void reduce_kernel(
    const float2* __restrict__ partials,
    float* __restrict__ inv_std) {
    int t = blockIdx.x * 256 + threadIdx.x;
    if (t >= BB * COUT) return;
    float s = 0.f, sq = 0.f;
    for (int k = 0; k < NTILE; ++k) {
        float2 p = partials[t * NTILE + k];
        s += p.x; sq += p.y;
    }
    const float N = 65536.f;
    float var = (sq - s * s / N) / (N - 1.f);   // unbiased (ddof=1)
    inv_std[t] = 1.0f / sqrtf(var);
}

// ---------------- scale: bf16 ws -> fp32 out ----------------
__global__ __launch_bounds__(256) void scale_bf16_kernel(
    const unsigned short* __restrict__ bf,
    const float* __restrict__ inv_std,
    float* __restrict__ out) {
    const int n8 = BB * COUT * HH * WW / 8;     // 4194304
    for (int i = blockIdx.x * 256 + threadIdx.x; i < n8; i += gridDim.x * 256) {
        float m = inv_std[i >> 13];             // (i*8)>>16
        u16x8 v = *(const u16x8*)&bf[i * 8];
        float4 a, c;
        a.x = __uint_as_float(((unsigned)v[0]) << 16) * m;
        a.y = __uint_as_float(((unsigned)v[1]) << 16) * m;
        a.z = __uint_as_float(((unsigned)v[2]) << 16) * m;
        a.w = __uint_as_float(((unsigned)v[3]) << 16) * m;
        c.x = __uint_as_float(((unsigned)v[4]) << 16) * m;
        c.y = __uint_as_float(((unsigned)v[5]) << 16) * m;
        c.z = __uint_as_float(((unsigned)v[6]) << 16) * m;
        c.w = __uint_as_float(((unsigned)v[7]) << 16) * m;
        *(float4*)&out[i * 8]     = a;
        *(float4*)&out[i * 8 + 4] = c;
    }
}

extern "C" void kernel_launch(void* const* d_in, const int* in_sizes, int n_in,
                              void* d_out, int out_size, void* d_ws, size_t ws_size,
                              hipStream_t stream) {
    const float* input      = (const float*)d_in[0];
    const float* style      = (const float*)d_in[1];
    const float* weight     = (const float*)d_in[2];
    const float* mod_weight = (const float*)d_in[3];
    const float* mod_bias   = (const float*)d_in[4];
    float* out = (float*)d_out;
    char*  ws  = (char*)d_ws;

    float*          s        = (float*)ws;                        // 2048 B
    unsigned short* Wk       = (unsigned short*)(ws + 2048);      // 589824 B
    float2*         partials = (float2*)(ws + 2048 + 589824);     // 1048576 B
    float*          inv      = (float*)(ws + 2048 + 589824 + 1048576);  // 2048 B
    float*          zbuf     = (float*)(ws + 2048 + 589824 + 1048576 + 2048); // 64 B
    const size_t    bf_off   = 2048 + 589824 + 1048576 + 2048 + 64;
    unsigned short* bfout    = (unsigned short*)(ws + bf_off);    // 67108864 B

    // NHWC bf16 intermediate lives in d_out's first 67MB; conv consumes it
    // before scale_bf16 overwrites all of d_out. Deterministic across replays.
    unsigned short* nhwc = (unsigned short*)d_out;

    prep_s_kernel<<<1, 512, 0, stream>>>(style, mod_weight, mod_bias, s, zbuf);
    prep_w_kernel<<<(BB * COUT * CIN * 9 + 255) / 256, 256, 0, stream>>>(
        weight, s, Wk);

    repack_kernel<<<4096, 256, 0, stream>>>(input, nhwc);
    conv_mfma_kernel<<<2048, 256, 0, stream>>>(nhwc, Wk, zbuf, bfout, partials);

    reduce_kernel<<<2, 256, 0, stream>>>(partials, inv);
    scale_bf16_kernel<<<2048, 256, 0, stream>>>(bfout, inv, out);
}

// Round 17
// 161.376 us; speedup vs baseline: 1.2358x; 1.0904x over previous
//
#include <hip/hip_runtime.h>
#include <math.h>

#define CIN   32
#define COUT  32
#define HH    256
#define WW    256
#define BB    16
#define SDIM  512

#define XT    16
#define YT    16
#define NXT   16
#define NTILE 256           // 16x16 tiles per (b,co)

typedef __attribute__((ext_vector_type(8))) short bf16x8;
typedef __attribute__((ext_vector_type(4))) float f32x4;
typedef __attribute__((ext_vector_type(8))) unsigned short u16x8;

__device__ __forceinline__ unsigned bf16_rne_bits(float x) {
    unsigned u = __float_as_uint(x);
    return (u + 0x7fffu + ((u >> 16) & 1u)) >> 16;   // round-nearest-even bf16
}

// ---------------- prep: s = style @ (mod_weight*mscale)^T + bias ----------------
// also zeroes the 64B OOB-source buffer used by conv's global_load_lds staging
__global__ __launch_bounds__(512) void prep_s_kernel(
    const float* __restrict__ style,
    const float* __restrict__ mod_weight,
    const float* __restrict__ mod_bias,
    float* __restrict__ s_out,
    float* __restrict__ zbuf) {
    int t = threadIdx.x;            // t -> (b, ci)
    if (t < 16) zbuf[t] = 0.f;
    int b = t >> 5, ci = t & 31;
    const float mscale = 0.044194173824159216f;  // 1/sqrt(512)
    const float* st = style + b * SDIM;
    const float* mw = mod_weight + ci * SDIM;
    float acc = 0.f;
    for (int d = 0; d < SDIM; d += 4) {
        acc += st[d]   * mw[d]
             + st[d+1] * mw[d+1]
             + st[d+2] * mw[d+2]
             + st[d+3] * mw[d+3];
    }
    s_out[t] = acc * mscale + mod_bias[ci];
}

// ---------------- prep: pack per-(b,window) modulated weights as bf16 hi/lo ------
// Layout: Wk[((b*9 + w)*2 + part)*1024 + co*32 + ci]  (ushort bf16 bits)
// (conv currently consumes only part 0 (hi); lo kept for easy fallback)
__global__ __launch_bounds__(256) void prep_w_kernel(
    const float* __restrict__ weight,
    const float* __restrict__ s,
    unsigned short* __restrict__ Wk) {
    int idx = blockIdx.x * 256 + threadIdx.x;   // over 16*32*32*9 = 147456
    if (idx >= BB * COUT * CIN * 9) return;
    const float wscale = 0.05892556509887896f;  // 1/sqrt(32*3*3)
    int b  = idx / (COUT * CIN * 9);
    int r  = idx % (COUT * CIN * 9);
    int co = r / (CIN * 9);
    int r2 = r % (CIN * 9);
    int ci = r2 / 9;
    int w  = r2 % 9;
    float wm = wscale * weight[co * (CIN * 9) + ci * 9 + w] * s[b * CIN + ci];
    unsigned hb = bf16_rne_bits(wm);
    float hif = __uint_as_float(hb << 16);
    unsigned lb = bf16_rne_bits(wm - hif);
    int base = ((b * 9 + w) * 2) * 1024 + co * 32 + ci;
    Wk[base]        = (unsigned short)hb;   // part 0: hi
    Wk[base + 1024] = (unsigned short)lb;   // part 1: lo
}

// ---------------- repack v2: NCHW fp32 -> slot-permuted NHWC bf16 --------------
// LDS-bounce transpose: stage A coalesced float4 reads -> lt[x][ci] (stride 40);
// stage B 16B LDS reads (<=2-way banks) -> perfectly contiguous 16B stores.
// chunk(b,gy,gx) = 64B of 32 ci; octet o at slot (o + ((gx+1)>>1))&3.
__global__ __launch_bounds__(256) void repack_kernel(
    const float* __restrict__ input,
    unsigned short* __restrict__ nhwc) {
    __shared__ __align__(16) unsigned short lt[256 * 40];   // 20 KB
    const int tid = threadIdx.x;
    const int gy = blockIdx.x & 255;
    const int b  = blockIdx.x >> 8;

    // stage A: 512 tasks (8 ci-quads x 64 float4), 2 per thread
    #pragma unroll
    for (int it = 0; it < 2; ++it) {
        int idx = it * 256 + tid;
        int xf  = idx & 63;             // x = 4*xf..+3
        int cg  = idx >> 6;             // ci = 4*cg..+3
        const float* ip = input + (((b * 32 + cg * 4) * 256 + gy) * 256) + xf * 4;
        float4 v0 = *(const float4*)(ip);
        float4 v1 = *(const float4*)(ip + 65536);
        float4 v2 = *(const float4*)(ip + 131072);
        float4 v3 = *(const float4*)(ip + 196608);
        float a0[4] = {v0.x, v0.y, v0.z, v0.w};
        float a1[4] = {v1.x, v1.y, v1.z, v1.w};
        float a2[4] = {v2.x, v2.y, v2.z, v2.w};
        float a3[4] = {v3.x, v3.y, v3.z, v3.w};
        #pragma unroll
        for (int m = 0; m < 4; ++m) {
            uint2 p;
            p.x = bf16_rne_bits(a0[m]) | (bf16_rne_bits(a1[m]) << 16);
            p.y = bf16_rne_bits(a2[m]) | (bf16_rne_bits(a3[m]) << 16);
            *(uint2*)&lt[(xf * 4 + m) * 40 + cg * 4] = p;
        }
    }
    __syncthreads();

    // stage B: 1024 tasks (256 gx x 4 slots), 4 per thread; lanes -> contiguous
    unsigned short* cb = nhwc + (((((b << 8) + gy) << 8)) << 5);
    #pragma unroll
    for (int it = 0; it < 4; ++it) {
        int idx  = it * 256 + tid;
        int slot = idx & 3;
        int gx   = idx >> 2;
        int o    = (slot - ((gx + 1) >> 1)) & 3;
        bf16x8 v = *(const bf16x8*)&lt[gx * 40 + o * 8];
        *(bf16x8*)(cb + (gx << 5) + slot * 8) = v;
    }
}

// ---------------- MFMA conv: global_load_lds staging, single weight term -------
// grid 4096 (XCD-swizzled), 4 waves, 6 blocks/CU (~21KB LDS).
// Staging: 1296 x 16B direct global->LDS DMA; LDS dest linear (base+lane*16),
// swizzle pre-baked in nhwc; OOB lanes read a 64B zero buffer.
// Error budget: x-bf16 ~0.031 absmax; dropping the weight-lo MFMA adds a
// symmetric ~0.031 term (threshold 0.117). Halves MFMA count + Wk traffic.
// NOTE: (256,6) is the measured local optimum — (512,8)/(256,7) spill;
// kw full-unroll +28us (r15); 2-tile dbuf loses occupancy +5us (r16).
__global__ __launch_bounds__(256, 6) void conv_mfma_kernel(
    const unsigned short* __restrict__ nhwc,
    const unsigned short* __restrict__ Wk,
    const float* __restrict__ zbuf,
    unsigned short* __restrict__ bfout,
    float2* __restrict__ partials) {

    __shared__ __align__(16) unsigned short xlds[18 * 576];
    __shared__ float2 stats[4 * 32];

    const int tid = threadIdx.x;
    // bijective XCD swizzle: each XCD gets 512 consecutive sw ids (2 b-slices)
    const int wg = blockIdx.x;
    const int sw = (wg & 7) * 512 + (wg >> 3);
    const int b  = sw >> 8;
    const int yt = (sw >> 4) & 15;
    const int xt = sw & 15;

    const int x0 = xt * XT, y0 = yt * YT;
    const int t  = tid & 15;
    const int g  = (tid >> 4) & 3;
    const int wv = tid >> 6;
    const int f  = wv & 1;
    const int rbase = 8 * (wv >> 1);

    // ---- staging: 1296 x 16B global->LDS DMA (6 per thread) ----
    #pragma unroll
    for (int it = 0; it < 6; ++it) {
        int idx = it * 256 + tid;
        if (idx < 1296) {
            int s  = idx & 3;
            int cu = idx >> 2;          // y*18 + u
            int u  = cu % 18;
            int y  = cu / 18;
            int gy = y0 - 1 + y, gx = x0 - 1 + u;
            bool ok = ((unsigned)gy < 256u) && ((unsigned)gx < 256u);
            const unsigned short* src = ok
                ? nhwc + (((((b << 8) + gy) << 8) + gx) << 5) + s * 8
                : (const unsigned short*)zbuf + s * 8;
            __builtin_amdgcn_global_load_lds(
                (const __attribute__((address_space(1))) unsigned int*)src,
                (__attribute__((address_space(3))) unsigned int*)
                    ((char*)xlds + (idx << 4)),
                16, 0, 0);
        }
    }
    __syncthreads();

    // ---- compute: 3 kw-passes, each {3 weight frags, 10 row frags, 24 MFMA} ----
    f32x4 acc[8];
    #pragma unroll
    for (int i = 0; i < 8; ++i) acc[i] = (f32x4){0.f, 0.f, 0.f, 0.f};

    #pragma unroll 1
    for (int kw = 0; kw < 3; ++kw) {
        const int u = t + kw;                    // 0..17, always staged
        const int slot = (g + (u >> 1)) & 3;

        bf16x8 wf[3];
        const unsigned short* wb =
            Wk + (b * 9 * 2) * 1024 + f * 512 + t * 32 + g * 8;
        #pragma unroll
        for (int kh = 0; kh < 3; ++kh)
            wf[kh] = *(const bf16x8*)(wb + ((kh * 3 + kw) * 2) * 1024);

        bf16x8 xv[10];
        #pragma unroll
        for (int y = 0; y < 10; ++y)
            xv[y] = *(const bf16x8*)&xlds[(rbase + y) * 576 + u * 32 + slot * 8];

        #pragma unroll
        for (int kh = 0; kh < 3; ++kh)
            #pragma unroll
            for (int i = 0; i < 8; ++i)
                acc[i] = __builtin_amdgcn_mfma_f32_16x16x32_bf16(
                    wf[kh], xv[i + kh], acc[i], 0, 0, 0);
    }

    // ---- epilogue: bf16 stores + stats ----
    float s_[4] = {0.f, 0.f, 0.f, 0.f}, q_[4] = {0.f, 0.f, 0.f, 0.f};
    #pragma unroll
    for (int i = 0; i < 8; ++i) {
        const int gy = y0 + rbase + i;
        #pragma unroll
        for (int r = 0; r < 4; ++r) {
            float v = acc[i][r];
            const int off = (b * 32 + 16 * f + 4 * g + r) * 65536 + gy * 256 + x0 + t;
            bfout[off] = (unsigned short)bf16_rne_bits(v);
            s_[r] += v;
            q_[r] += v * v;
        }
    }
    #pragma unroll
    for (int r = 0; r < 4; ++r) {
        #pragma unroll
        for (int off = 1; off < 16; off <<= 1) {
            s_[r] += __shfl_xor(s_[r], off);
            q_[r] += __shfl_xor(q_[r], off);
        }
    }
    if (t == 0) {
        #pragma unroll
        for (int r = 0; r < 4; ++r)
            stats[wv * 32 + 16 * f + 4 * g + r] = make_float2(s_[r], q_[r]);
    }
    __syncthreads();
    if (tid < 32) {
        int w0 = (tid < 16) ? 0 : 1;            // waves 0/2 own co<16, 1/3 co>=16
        float2 a = stats[w0 * 32 + tid];
        float2 c = stats[(w0 + 2) * 32 + tid];
        partials[(b * 32 + tid) * NTILE + yt * NXT + xt] =
            make_float2(a.x + c.x, a.y + c.y);
    }
}

// ---------------- fold tile partials -> inv std ----------------
__global__ __launch_bounds__(256) void reduce_kernel(
    const float2* __restrict__ partials,
    float* __restrict__ inv_std) {
    int t = blockIdx.x * 256 + threadIdx.x;
    if (t >= BB * COUT) return;
    float s = 0.f, sq = 0.f;
    for (int k = 0; k < NTILE; ++k) {
        float2 p = partials[t * NTILE + k];
        s += p.x; sq += p.y;
    }
    const float N = 65536.f;
    float var = (sq - s * s / N) / (N - 1.f);   // unbiased (ddof=1)
    inv_std[t] = 1.0f / sqrtf(var);
}

// ---------------- scale: bf16 ws -> fp32 out ----------------
__global__ __launch_bounds__(256) void scale_bf16_kernel(
    const unsigned short* __restrict__ bf,
    const float* __restrict__ inv_std,
    float* __restrict__ out) {
    const int n8 = BB * COUT * HH * WW / 8;     // 4194304
    for (int i = blockIdx.x * 256 + threadIdx.x; i < n8; i += gridDim.x * 256) {
        float m = inv_std[i >> 13];             // (i*8)>>16
        u16x8 v = *(const u16x8*)&bf[i * 8];
        float4 a, c;
        a.x = __uint_as_float(((unsigned)v[0]) << 16) * m;
        a.y = __uint_as_float(((unsigned)v[1]) << 16) * m;
        a.z = __uint_as_float(((unsigned)v[2]) << 16) * m;
        a.w = __uint_as_float(((unsigned)v[3]) << 16) * m;
        c.x = __uint_as_float(((unsigned)v[4]) << 16) * m;
        c.y = __uint_as_float(((unsigned)v[5]) << 16) * m;
        c.z = __uint_as_float(((unsigned)v[6]) << 16) * m;
        c.w = __uint_as_float(((unsigned)v[7]) << 16) * m;
        *(float4*)&out[i * 8]     = a;
        *(float4*)&out[i * 8 + 4] = c;
    }
}

extern "C" void kernel_launch(void* const* d_in, const int* in_sizes, int n_in,
                              void* d_out, int out_size, void* d_ws, size_t ws_size,
                              hipStream_t stream) {
    const float* input      = (const float*)d_in[0];
    const float* style      = (const float*)d_in[1];
    const float* weight     = (const float*)d_in[2];
    const float* mod_weight = (const float*)d_in[3];
    const float* mod_bias   = (const float*)d_in[4];
    float* out = (float*)d_out;
    char*  ws  = (char*)d_ws;

    float*          s        = (float*)ws;                        // 2048 B
    unsigned short* Wk       = (unsigned short*)(ws + 2048);      // 589824 B
    float2*         partials = (float2*)(ws + 2048 + 589824);     // 1048576 B
    float*          inv      = (float*)(ws + 2048 + 589824 + 1048576);  // 2048 B
    float*          zbuf     = (float*)(ws + 2048 + 589824 + 1048576 + 2048); // 64 B
    const size_t    bf_off   = 2048 + 589824 + 1048576 + 2048 + 64;
    unsigned short* bfout    = (unsigned short*)(ws + bf_off);    // 67108864 B

    // NHWC bf16 intermediate lives in d_out's first 67MB; conv consumes it
    // before scale_bf16 overwrites all of d_out. Deterministic across replays.
    unsigned short* nhwc = (unsigned short*)d_out;

    prep_s_kernel<<<1, 512, 0, stream>>>(style, mod_weight, mod_bias, s, zbuf);
    prep_w_kernel<<<(BB * COUT * CIN * 9 + 255) / 256, 256, 0, stream>>>(
        weight, s, Wk);

    repack_kernel<<<4096, 256, 0, stream>>>(input, nhwc);
    conv_mfma_kernel<<<4096, 256, 0, stream>>>(nhwc, Wk, zbuf, bfout, partials);

    reduce_kernel<<<2, 256, 0, stream>>>(partials, inv);
    scale_bf16_kernel<<<2048, 256, 0, stream>>>(bfout, inv, out);
}

// Round 18
// 113.182 us; speedup vs baseline: 1.7620x; 1.4258x over previous
//
#include <hip/hip_runtime.h>
#include <math.h>

#define CIN   32
#define COUT  32
#define HH    256
#define WW    256
#define BB    16
#define SDIM  512

#define XT    16
#define YT    16
#define NXT   16
#define NTILE 256           // 16x16 tiles per (b,co)

typedef __attribute__((ext_vector_type(8))) short bf16x8;
typedef __attribute__((ext_vector_type(4))) float f32x4;
typedef __attribute__((ext_vector_type(8))) unsigned short u16x8;

__device__ __forceinline__ unsigned bf16_rne_bits(float x) {
    unsigned u = __float_as_uint(x);
    return (u + 0x7fffu + ((u >> 16) & 1u)) >> 16;   // round-nearest-even bf16
}

// ---------------- fused prep+repack ----------------
// grid 4672: bid<4096 -> repack (NCHW fp32 -> slot-permuted NHWC bf16, LDS-bounce);
//            bid>=4096 -> weight prep (s in LDS, then wmod hi/lo pack).
// Paths independent; block 4096 also zeroes the 64B OOB buffer for conv staging.
__global__ __launch_bounds__(256) void fused_prep_kernel(
    const float* __restrict__ input,
    const float* __restrict__ style,
    const float* __restrict__ mod_weight,
    const float* __restrict__ mod_bias,
    const float* __restrict__ weight,
    unsigned short* __restrict__ nhwc,
    unsigned short* __restrict__ Wk,
    float* __restrict__ zbuf) {
    __shared__ __align__(16) unsigned short lt[256 * 40];   // 20 KB (union)
    const int bid = blockIdx.x;
    const int tid = threadIdx.x;

    if (bid < 4096) {
        // ---- repack path (identical to r17 repack_kernel) ----
        const int gy = bid & 255;
        const int b  = bid >> 8;

        #pragma unroll
        for (int it = 0; it < 2; ++it) {
            int idx = it * 256 + tid;
            int xf  = idx & 63;             // x = 4*xf..+3
            int cg  = idx >> 6;             // ci = 4*cg..+3
            const float* ip = input + (((b * 32 + cg * 4) * 256 + gy) * 256) + xf * 4;
            float4 v0 = *(const float4*)(ip);
            float4 v1 = *(const float4*)(ip + 65536);
            float4 v2 = *(const float4*)(ip + 131072);
            float4 v3 = *(const float4*)(ip + 196608);
            float a0[4] = {v0.x, v0.y, v0.z, v0.w};
            float a1[4] = {v1.x, v1.y, v1.z, v1.w};
            float a2[4] = {v2.x, v2.y, v2.z, v2.w};
            float a3[4] = {v3.x, v3.y, v3.z, v3.w};
            #pragma unroll
            for (int m = 0; m < 4; ++m) {
                uint2 p;
                p.x = bf16_rne_bits(a0[m]) | (bf16_rne_bits(a1[m]) << 16);
                p.y = bf16_rne_bits(a2[m]) | (bf16_rne_bits(a3[m]) << 16);
                *(uint2*)&lt[(xf * 4 + m) * 40 + cg * 4] = p;
            }
        }
        __syncthreads();

        unsigned short* cb = nhwc + (((((b << 8) + gy) << 8)) << 5);
        #pragma unroll
        for (int it = 0; it < 4; ++it) {
            int idx  = it * 256 + tid;
            int slot = idx & 3;
            int gx   = idx >> 2;
            int o    = (slot - ((gx + 1) >> 1)) & 3;
            bf16x8 v = *(const bf16x8*)&lt[gx * 40 + o * 8];
            *(bf16x8*)(cb + (gx << 5) + slot * 8) = v;
        }
    } else {
        // ---- weight prep path: 576 blocks, 36 per batch ----
        const int wblk = bid - 4096;            // 0..575
        const int b    = wblk / 36;             // single b per block
        if (wblk == 0 && tid < 16) zbuf[tid] = 0.f;

        float* s_lds = (float*)lt;
        if (tid < 32) {
            const int ci = tid;
            const float mscale = 0.044194173824159216f;  // 1/sqrt(512)
            const float* st = style + b * SDIM;
            const float* mw = mod_weight + ci * SDIM;
            float acc = 0.f;
            for (int d = 0; d < SDIM; d += 4) {
                acc += st[d]   * mw[d]
                     + st[d+1] * mw[d+1]
                     + st[d+2] * mw[d+2]
                     + st[d+3] * mw[d+3];
            }
            s_lds[ci] = acc * mscale + mod_bias[ci];
        }
        __syncthreads();

        const int idx = wblk * 256 + tid;       // < 147456 always
        const float wscale = 0.05892556509887896f;   // 1/sqrt(32*3*3)
        int r  = idx % (COUT * CIN * 9);        // same b as block-level
        int co = r / (CIN * 9);
        int r2 = r % (CIN * 9);
        int ci = r2 / 9;
        int w  = r2 % 9;
        float wm = wscale * weight[co * (CIN * 9) + ci * 9 + w] * s_lds[ci];
        unsigned hb = bf16_rne_bits(wm);
        float hif = __uint_as_float(hb << 16);
        unsigned lb = bf16_rne_bits(wm - hif);
        int base = ((b * 9 + w) * 2) * 1024 + co * 32 + ci;
        Wk[base]        = (unsigned short)hb;   // part 0: hi (consumed)
        Wk[base + 1024] = (unsigned short)lb;   // part 1: lo (fallback only)
    }
}

// ---------------- MFMA conv: global_load_lds staging, single weight term -------
// grid 4096 (XCD-swizzled), 4 waves, 6 blocks/CU (~21KB LDS).
// Staging: 1296 x 16B direct global->LDS DMA; LDS dest linear (base+lane*16),
// swizzle pre-baked in nhwc; OOB lanes read a 64B zero buffer.
// Error budget: x-bf16 ~0.031 absmax; single-term weights measured no change.
// NOTE: (256,6) is the measured local optimum — (512,8)/(256,7) spill;
// kw full-unroll +28us (r15); 2-tile dbuf loses occupancy +5us (r16).
__global__ __launch_bounds__(256, 6) void conv_mfma_kernel(
    const unsigned short* __restrict__ nhwc,
    const unsigned short* __restrict__ Wk,
    const float* __restrict__ zbuf,
    unsigned short* __restrict__ bfout,
    float2* __restrict__ partials) {

    __shared__ __align__(16) unsigned short xlds[18 * 576];
    __shared__ float2 stats[4 * 32];

    const int tid = threadIdx.x;
    // bijective XCD swizzle: each XCD gets 512 consecutive sw ids (2 b-slices)
    const int wg = blockIdx.x;
    const int sw = (wg & 7) * 512 + (wg >> 3);
    const int b  = sw >> 8;
    const int yt = (sw >> 4) & 15;
    const int xt = sw & 15;

    const int x0 = xt * XT, y0 = yt * YT;
    const int t  = tid & 15;
    const int g  = (tid >> 4) & 3;
    const int wv = tid >> 6;
    const int f  = wv & 1;
    const int rbase = 8 * (wv >> 1);

    // ---- staging: 1296 x 16B global->LDS DMA (6 per thread) ----
    #pragma unroll
    for (int it = 0; it < 6; ++it) {
        int idx = it * 256 + tid;
        if (idx < 1296) {
            int s  = idx & 3;
            int cu = idx >> 2;          // y*18 + u
            int u  = cu % 18;
            int y  = cu / 18;
            int gy = y0 - 1 + y, gx = x0 - 1 + u;
            bool ok = ((unsigned)gy < 256u) && ((unsigned)gx < 256u);
            const unsigned short* src = ok
                ? nhwc + (((((b << 8) + gy) << 8) + gx) << 5) + s * 8
                : (const unsigned short*)zbuf + s * 8;
            __builtin_amdgcn_global_load_lds(
                (const __attribute__((address_space(1))) unsigned int*)src,
                (__attribute__((address_space(3))) unsigned int*)
                    ((char*)xlds + (idx << 4)),
                16, 0, 0);
        }
    }
    __syncthreads();

    // ---- compute: 3 kw-passes, each {3 weight frags, 10 row frags, 24 MFMA} ----
    f32x4 acc[8];
    #pragma unroll
    for (int i = 0; i < 8; ++i) acc[i] = (f32x4){0.f, 0.f, 0.f, 0.f};

    #pragma unroll 1
    for (int kw = 0; kw < 3; ++kw) {
        const int u = t + kw;                    // 0..17, always staged
        const int slot = (g + (u >> 1)) & 3;

        bf16x8 wf[3];
        const unsigned short* wb =
            Wk + (b * 9 * 2) * 1024 + f * 512 + t * 32 + g * 8;
        #pragma unroll
        for (int kh = 0; kh < 3; ++kh)
            wf[kh] = *(const bf16x8*)(wb + ((kh * 3 + kw) * 2) * 1024);

        bf16x8 xv[10];
        #pragma unroll
        for (int y = 0; y < 10; ++y)
            xv[y] = *(const bf16x8*)&xlds[(rbase + y) * 576 + u * 32 + slot * 8];

        #pragma unroll
        for (int kh = 0; kh < 3; ++kh)
            #pragma unroll
            for (int i = 0; i < 8; ++i)
                acc[i] = __builtin_amdgcn_mfma_f32_16x16x32_bf16(
                    wf[kh], xv[i + kh], acc[i], 0, 0, 0);
    }

    // ---- epilogue: bf16 stores + stats ----
    float s_[4] = {0.f, 0.f, 0.f, 0.f}, q_[4] = {0.f, 0.f, 0.f, 0.f};
    #pragma unroll
    for (int i = 0; i < 8; ++i) {
        const int gy = y0 + rbase + i;
        #pragma unroll
        for (int r = 0; r < 4; ++r) {
            float v = acc[i][r];
            const int off = (b * 32 + 16 * f + 4 * g + r) * 65536 + gy * 256 + x0 + t;
            bfout[off] = (unsigned short)bf16_rne_bits(v);
            s_[r] += v;
            q_[r] += v * v;
        }
    }
    #pragma unroll
    for (int r = 0; r < 4; ++r) {
        #pragma unroll
        for (int off = 1; off < 16; off <<= 1) {
            s_[r] += __shfl_xor(s_[r], off);
            q_[r] += __shfl_xor(q_[r], off);
        }
    }
    if (t == 0) {
        #pragma unroll
        for (int r = 0; r < 4; ++r)
            stats[wv * 32 + 16 * f + 4 * g + r] = make_float2(s_[r], q_[r]);
    }
    __syncthreads();
    if (tid < 32) {
        int w0 = (tid < 16) ? 0 : 1;            // waves 0/2 own co<16, 1/3 co>=16
        float2 a = stats[w0 * 32 + tid];
        float2 c = stats[(w0 + 2) * 32 + tid];
        partials[(b * 32 + tid) * NTILE + yt * NXT + xt] =
            make_float2(a.x + c.x, a.y + c.y);
    }
}

// ---------------- fused reduce+scale: 4 blocks per (b,co) channel --------------
// Each block re-reduces its channel's 256 tile-partials (2KB, L2-hit after the
// first block) -> inv_std in LDS (no global round-trip), then scales its
// 16384-element quarter-channel from bf16 ws to fp32 out.
__global__ __launch_bounds__(256) void reduce_scale_kernel(
    const float2* __restrict__ partials,
    const unsigned short* __restrict__ bf,
    float* __restrict__ out) {
    __shared__ float wsum[4], wsq[4];
    __shared__ float inv_s;
    const int bid = blockIdx.x;
    const int c   = bid >> 2;          // channel 0..511
    const int q   = bid & 3;           // quarter
    const int tid = threadIdx.x;

    float2 p = partials[c * 256 + tid];
    float s = p.x, sq = p.y;
    #pragma unroll
    for (int off = 1; off < 64; off <<= 1) {
        s  += __shfl_xor(s,  off);
        sq += __shfl_xor(sq, off);
    }
    if ((tid & 63) == 0) { wsum[tid >> 6] = s; wsq[tid >> 6] = sq; }
    __syncthreads();
    if (tid == 0) {
        float S = wsum[0] + wsum[1] + wsum[2] + wsum[3];
        float Q = wsq[0]  + wsq[1]  + wsq[2]  + wsq[3];
        const float N = 65536.f;
        float var = (Q - S * S / N) / (N - 1.f);   // unbiased (ddof=1)
        inv_s = 1.0f / sqrtf(var);
    }
    __syncthreads();
    const float m = inv_s;

    const unsigned short* src = bf  + c * 65536 + q * 16384;
    float*                dst = out + c * 65536 + q * 16384;
    #pragma unroll
    for (int it = 0; it < 8; ++it) {
        int i = (it * 256 + tid) * 8;
        u16x8 v = *(const u16x8*)&src[i];
        float4 a, cc;
        a.x  = __uint_as_float(((unsigned)v[0]) << 16) * m;
        a.y  = __uint_as_float(((unsigned)v[1]) << 16) * m;
        a.z  = __uint_as_float(((unsigned)v[2]) << 16) * m;
        a.w  = __uint_as_float(((unsigned)v[3]) << 16) * m;
        cc.x = __uint_as_float(((unsigned)v[4]) << 16) * m;
        cc.y = __uint_as_float(((unsigned)v[5]) << 16) * m;
        cc.z = __uint_as_float(((unsigned)v[6]) << 16) * m;
        cc.w = __uint_as_float(((unsigned)v[7]) << 16) * m;
        *(float4*)&dst[i]     = a;
        *(float4*)&dst[i + 4] = cc;
    }
}

extern "C" void kernel_launch(void* const* d_in, const int* in_sizes, int n_in,
                              void* d_out, int out_size, void* d_ws, size_t ws_size,
                              hipStream_t stream) {
    const float* input      = (const float*)d_in[0];
    const float* style      = (const float*)d_in[1];
    const float* weight     = (const float*)d_in[2];
    const float* mod_weight = (const float*)d_in[3];
    const float* mod_bias   = (const float*)d_in[4];
    float* out = (float*)d_out;
    char*  ws  = (char*)d_ws;

    unsigned short* Wk       = (unsigned short*)(ws + 2048);      // 589824 B
    float2*         partials = (float2*)(ws + 2048 + 589824);     // 1048576 B
    float*          zbuf     = (float*)(ws + 2048 + 589824 + 1048576 + 2048); // 64 B
    const size_t    bf_off   = 2048 + 589824 + 1048576 + 2048 + 64;
    unsigned short* bfout    = (unsigned short*)(ws + bf_off);    // 67108864 B

    // NHWC bf16 intermediate lives in d_out's first 67MB; conv consumes it
    // before reduce_scale overwrites all of d_out. Deterministic across replays.
    unsigned short* nhwc = (unsigned short*)d_out;

    fused_prep_kernel<<<4672, 256, 0, stream>>>(
        input, style, mod_weight, mod_bias, weight, nhwc, Wk, zbuf);
    conv_mfma_kernel<<<4096, 256, 0, stream>>>(nhwc, Wk, zbuf, bfout, partials);
    reduce_scale_kernel<<<2048, 256, 0, stream>>>(partials, bfout, out);
}